// Round 4
// baseline (126.765 us; speedup 1.0000x reference)
//
#include <hip/hip_runtime.h>
#include <hip/hip_bf16.h>

// RBF kernel matrix: out[i][j] = exp(-gamma * max(x2[i] + y2[j] - 2*x.y, 0))
//
// Round 4: persistent-strip MFMA kernel.
//  - prep: fp32 norms + bf16 hi/lo split into d_ws as pre-swizzled row images.
//  - main: 512 blocks (2/CU), 256 threads (4 waves). Block b owns X panel
//    b/8 (staged to LDS ONCE) and sweeps JT=8 consecutive j-tiles of 128.
//    Per tile: preload all Y fragments LDS->reg, barrier, issue NEXT tile's
//    Y DMA (global_load_lds w16) so its latency hides under this tile's
//    96 MFMAs + exp epilogue. j-group = b%8 aligns with XCD round-robin ->
//    each XCD's L2 keeps its 8 Y panels resident all kernel.
//  - 3 MFMA passes (hi*hi + lo*hi + hi*lo), drop lo*lo (~1e-21 abs out err).
//  - epilogue: out = 2^(min(c*x2 + c*y2 + 2|c|*xy, 0)), c = -g*log2e,
//    NON-TEMPORAL float4 stores (output is write-once; keep L2 for tiles).
// Write floor: 268 MB @ ~6.9 TB/s (fill-kernel calibrated) ~= 39 us.

#define DD 64
#define BM 128
#define BN 128
#define JT 8

typedef __attribute__((ext_vector_type(8))) short short8;
typedef __attribute__((ext_vector_type(4))) float f32x4;

#if __has_builtin(__builtin_amdgcn_exp2f)
#define EXP2(x) __builtin_amdgcn_exp2f(x)
#else
#define EXP2(x) exp2f(x)
#endif

__device__ __forceinline__ unsigned short f2bf_rne(float f) {
  unsigned u = __float_as_uint(f);
  unsigned r = u + 0x7FFFu + ((u >> 16) & 1u);
  return (unsigned short)(r >> 16);
}

// ---------------- prep: fp32 norms + bf16 hi/lo pre-split (pre-swizzled) ----
__global__ __launch_bounds__(256)
void prep_split(const float* __restrict__ X, const float* __restrict__ Y,
                unsigned short* __restrict__ XHg, unsigned short* __restrict__ XLg,
                unsigned short* __restrict__ YHg, unsigned short* __restrict__ YLg,
                float* __restrict__ xsq, float* __restrict__ ysq, int n) {
  int t = blockIdx.x * 256 + threadIdx.x;
  int row = t >> 4;       // 16 lanes per row
  int c4 = t & 15;        // float4 index within row
  const float* src;
  unsigned short *hd, *ld;
  float* nd;
  int r;
  if (row < n) { r = row;     src = X + (long)r * DD; hd = XHg; ld = XLg; nd = xsq + r; }
  else         { r = row - n; src = Y + (long)r * DD; hd = YHg; ld = YLg; nd = ysq + r; }
  float4 v = ((const float4*)src)[c4];
  float f[4] = {v.x, v.y, v.z, v.w};
  unsigned short h[4], l[4];
#pragma unroll
  for (int q = 0; q < 4; ++q) {
    h[q] = f2bf_rne(f[q]);
    float hv = __uint_as_float(((unsigned)h[q]) << 16);
    l[q] = f2bf_rne(f[q] - hv);
  }
  int sw = (c4 * 8) ^ ((r & 7) << 4);   // swizzled byte offset within 128-B row
  *(ushort4*)((char*)hd + (long)r * 128 + sw) = make_ushort4(h[0], h[1], h[2], h[3]);
  *(ushort4*)((char*)ld + (long)r * 128 + sw) = make_ushort4(l[0], l[1], l[2], l[3]);
  float s = v.x * v.x + v.y * v.y + v.z * v.z + v.w * v.w;
  s += __shfl_xor(s, 1);
  s += __shfl_xor(s, 2);
  s += __shfl_xor(s, 4);
  s += __shfl_xor(s, 8);
  if (c4 == 0) *nd = s;
}

// ---------------- main: persistent strip, pipelined Y staging --------------
__global__ __launch_bounds__(256, 2)
void rbf_persist(const unsigned short* __restrict__ XHg, const unsigned short* __restrict__ XLg,
                 const unsigned short* __restrict__ YHg, const unsigned short* __restrict__ YLg,
                 const float* __restrict__ gptr,
                 const float* __restrict__ xsq, const float* __restrict__ ysq,
                 float* __restrict__ Out, int mcols, int jb) {
  // [0,16K) XH panel  [16K,32K) XL  [32K,48K) YH(cur)  [48K,64K) YL(cur)
  __shared__ __align__(128) char lds[65536];

  const int tid = threadIdx.x;
  const int lane = tid & 63;
  const int wid = tid >> 6;          // 0..3
  const int b = blockIdx.x;
  const int jg = b % jb;             // j-group: aligns with XCD round-robin
  const int ip = b / jb;             // X panel index
  const long i0 = (long)ip * BM;

  // ---- prologue stage: XH, XL, YH(tile0), YL(tile0) — 4 x 16 KB DMA
  {
    const long jy0 = (long)jg * JT * BN * 128;   // byte offset of first Y panel
    const char* srcs[4] = {(const char*)XHg + i0 * 128, (const char*)XLg + i0 * 128,
                           (const char*)YHg + jy0,      (const char*)YLg + jy0};
#pragma unroll
    for (int t4 = 0; t4 < 4; ++t4) {
#pragma unroll
      for (int it = 0; it < 4; ++it) {
        int off = it * 4096 + wid * 1024;           // wave-uniform
        const char* g = srcs[t4] + off + lane * 16; // per-lane global src
        __builtin_amdgcn_global_load_lds(
            (const __attribute__((address_space(1))) void*)g,
            (__attribute__((address_space(3))) void*)(lds + t4 * 16384 + off),
            16, 0, 0);
      }
    }
  }

  const int wr = wid >> 1, wc = wid & 1;
  const int lr = lane & 15;
  const int hg = lane >> 4;          // 0..3

  const float g = *gptr;
  const float cf = -g * 1.4426950408889634f;   // -gamma * log2(e)
  const float nc2 = -2.0f * cf;
  float cxr[4];
#pragma unroll
  for (int m2 = 0; m2 < 4; ++m2) cxr[m2] = cf * xsq[i0 + wr * 64 + m2 * 16 + lr];

  __syncthreads();   // prologue DMA complete (vmcnt drained by compiler)

  for (int t = 0; t < JT; ++t) {
    const long j0 = ((long)jg * JT + t) * BN;

    // ---- preload ALL Y fragments for this tile into registers
    short8 bf[2][2][4];   // [img: YH/YL][kstep][n2]
#pragma unroll
    for (int im = 0; im < 2; ++im)
#pragma unroll
      for (int s = 0; s < 2; ++s)
#pragma unroll
        for (int n2 = 0; n2 < 4; ++n2) {
          int row = wc * 64 + n2 * 16 + lr;
          bf[im][s][n2] = *(const short8*)(lds + 32768 + im * 16384 + row * 128 +
                                           ((s * 64 + hg * 16) ^ ((row & 7) << 4)));
        }
    __syncthreads();   // block-wide: all Y(t) reads done before DMA overwrites

    // ---- issue next tile's Y DMA; latency hides under MFMA + epilogue
    if (t + 1 < JT) {
      const char* yh = (const char*)YHg + (j0 + BN) * 128;
      const char* yl = (const char*)YLg + (j0 + BN) * 128;
#pragma unroll
      for (int it = 0; it < 4; ++it) {
        int off = it * 4096 + wid * 1024;
        __builtin_amdgcn_global_load_lds(
            (const __attribute__((address_space(1))) void*)(yh + off + lane * 16),
            (__attribute__((address_space(3))) void*)(lds + 32768 + off), 16, 0, 0);
        __builtin_amdgcn_global_load_lds(
            (const __attribute__((address_space(1))) void*)(yl + off + lane * 16),
            (__attribute__((address_space(3))) void*)(lds + 49152 + off), 16, 0, 0);
      }
    }

    // ---- 3 MFMA passes (X frags re-read from LDS; X region never overwritten)
    f32x4 acc[4][4];
#pragma unroll
    for (int a = 0; a < 4; ++a)
#pragma unroll
      for (int c = 0; c < 4; ++c) acc[a][c] = (f32x4){0.f, 0.f, 0.f, 0.f};

    const int AOFF[3] = {0, 16384, 0};   // XH, XL, XH
    const int BIMG[3] = {0, 0, 1};       // YH, YH, YL
#pragma unroll
    for (int p = 0; p < 3; ++p) {
#pragma unroll
      for (int s = 0; s < 2; ++s) {
        short8 af[4];
#pragma unroll
        for (int m2 = 0; m2 < 4; ++m2) {
          int row = wr * 64 + m2 * 16 + lr;
          af[m2] = *(const short8*)(lds + AOFF[p] + row * 128 +
                                    ((s * 64 + hg * 16) ^ ((row & 7) << 4)));
        }
        // Swapped operands: reg dim = Y rows (output cols), lane&15 = X rows.
#pragma unroll
        for (int m2 = 0; m2 < 4; ++m2)
#pragma unroll
          for (int n2 = 0; n2 < 4; ++n2)
            acc[m2][n2] = __builtin_amdgcn_mfma_f32_16x16x32_bf16(
                bf[BIMG[p]][s][n2], af[m2], acc[m2][n2], 0, 0, 0);
      }
    }

    // ---- epilogue: out = 2^(min(c*x2 + c*y2 + 2|c|*xy, 0)), NT float4 stores
    float4 cyv[4];
#pragma unroll
    for (int n2 = 0; n2 < 4; ++n2) {
      float4 yq = *(const float4*)&ysq[j0 + wc * 64 + n2 * 16 + hg * 4];
      cyv[n2] = make_float4(cf * yq.x, cf * yq.y, cf * yq.z, cf * yq.w);
    }
#pragma unroll
    for (int m2 = 0; m2 < 4; ++m2) {
      long row = i0 + wr * 64 + m2 * 16 + lr;
      float* op = Out + row * (long)mcols + j0 + wc * 64 + hg * 4;
#pragma unroll
      for (int n2 = 0; n2 < 4; ++n2) {
        float cy[4] = {cyv[n2].x, cyv[n2].y, cyv[n2].z, cyv[n2].w};
        f32x4 o;
#pragma unroll
        for (int j = 0; j < 4; ++j)
          o[j] = EXP2(fminf(fmaf(nc2, acc[m2][n2][j], cxr[m2] + cy[j]), 0.f));
        __builtin_nontemporal_store(o, (f32x4*)(op + n2 * 16));
      }
    }
    __syncthreads();   // Y(t+1) DMA landed + stores flushed (vmcnt 0)
  }
}

// ---------------- fallback (proven round-2 path) ---------------------------
__global__ __launch_bounds__(256)
void prep_sq(const float* __restrict__ X, const float* __restrict__ Y,
             float* __restrict__ xsq, float* __restrict__ ysq, int n) {
  int t = blockIdx.x * 256 + threadIdx.x;
  int row = t >> 4;
  int c = t & 15;
  const float* src;
  float* dst;
  if (row < n) { src = X + (long)row * DD; dst = xsq + row; }
  else         { src = Y + (long)(row - n) * DD; dst = ysq + (row - n); }
  float4 v = ((const float4*)src)[c];
  float s = v.x * v.x + v.y * v.y + v.z * v.z + v.w * v.w;
  s += __shfl_xor(s, 1);
  s += __shfl_xor(s, 2);
  s += __shfl_xor(s, 4);
  s += __shfl_xor(s, 8);
  if (c == 0) *dst = s;
}

__global__ __launch_bounds__(256, 2)
void rbf_mfma_fb(const float* __restrict__ X, const float* __restrict__ Y,
                 const float* __restrict__ gptr,
                 const float* __restrict__ xsq, const float* __restrict__ ysq,
                 float* __restrict__ Out, int mcols) {
  __shared__ unsigned short XH[BM * DD], XL[BM * DD];
  __shared__ unsigned short YH[BN * DD], YL[BN * DD];
  const int tid = threadIdx.x;
  const long i0 = (long)blockIdx.y * BM;
  const long j0 = (long)blockIdx.x * BN;
#pragma unroll
  for (int it = 0; it < 16; ++it) {
    int e = it * 256 + tid;
    int half = e >> 11;
    int idx = e & 2047;
    int row = idx >> 4;
    int c4 = idx & 15;
    const float* src = half ? (Y + (j0 + row) * DD) : (X + (i0 + row) * DD);
    float4 v = ((const float4*)src)[c4];
    float f[4] = {v.x, v.y, v.z, v.w};
    unsigned short h[4], l[4];
#pragma unroll
    for (int q = 0; q < 4; ++q) {
      h[q] = f2bf_rne(f[q]);
      float hv = __uint_as_float(((unsigned)h[q]) << 16);
      l[q] = f2bf_rne(f[q] - hv);
    }
    int sw = (c4 * 8) ^ ((row & 7) << 4);
    unsigned short* Ht = half ? YH : XH;
    unsigned short* Lt = half ? YL : XL;
    *(ushort4*)((char*)Ht + row * 128 + sw) = make_ushort4(h[0], h[1], h[2], h[3]);
    *(ushort4*)((char*)Lt + row * 128 + sw) = make_ushort4(l[0], l[1], l[2], l[3]);
  }
  __syncthreads();
  const int lane = tid & 63;
  const int wid = tid >> 6;
  const int wr = wid >> 1, wc = wid & 1;
  const int lr = lane & 15;
  const int hg = lane >> 4;
  f32x4 acc[4][4];
#pragma unroll
  for (int a = 0; a < 4; ++a)
#pragma unroll
    for (int c = 0; c < 4; ++c) acc[a][c] = (f32x4){0.f, 0.f, 0.f, 0.f};
  const unsigned short* At[3] = {XH, XL, XH};
  const unsigned short* Bt[3] = {YH, YH, YL};
#pragma unroll
  for (int p = 0; p < 3; ++p) {
#pragma unroll
    for (int s = 0; s < 2; ++s) {
      const int kbyte = s * 64 + hg * 16;
      short8 af[4], bfv[4];
#pragma unroll
      for (int m2 = 0; m2 < 4; ++m2) {
        int row = wr * 64 + m2 * 16 + lr;
        af[m2] = *(const short8*)((const char*)At[p] + row * 128 + (kbyte ^ ((row & 7) << 4)));
      }
#pragma unroll
      for (int n2 = 0; n2 < 4; ++n2) {
        int row = wc * 64 + n2 * 16 + lr;
        bfv[n2] = *(const short8*)((const char*)Bt[p] + row * 128 + (kbyte ^ ((row & 7) << 4)));
      }
#pragma unroll
      for (int m2 = 0; m2 < 4; ++m2)
#pragma unroll
        for (int n2 = 0; n2 < 4; ++n2)
          acc[m2][n2] = __builtin_amdgcn_mfma_f32_16x16x32_bf16(af[m2], bfv[n2], acc[m2][n2], 0, 0, 0);
    }
  }
  const float g = *gptr;
  float yv[4];
#pragma unroll
  for (int n2 = 0; n2 < 4; ++n2) yv[n2] = ysq[j0 + wc * 64 + n2 * 16 + lr];
#pragma unroll
  for (int m2 = 0; m2 < 4; ++m2) {
#pragma unroll
    for (int j = 0; j < 4; ++j) {
      long row = i0 + wr * 64 + m2 * 16 + hg * 4 + j;
      float xr = xsq[row];
      float* op = Out + row * (long)mcols + j0 + wc * 64 + lr;
#pragma unroll
      for (int n2 = 0; n2 < 4; ++n2) {
        float d = fmaxf(xr + yv[n2] - 2.0f * acc[m2][n2][j], 0.f);
        op[n2 * 16] = __expf(-g * d);
      }
    }
  }
}

extern "C" void kernel_launch(void* const* d_in, const int* in_sizes, int n_in,
                              void* d_out, int out_size, void* d_ws, size_t ws_size,
                              hipStream_t stream) {
  const float* x = (const float*)d_in[0];
  const float* y = (const float*)d_in[1];
  const float* g = (const float*)d_in[2];
  float* out = (float*)d_out;

  const int n = in_sizes[0] / DD;   // 8192
  const int m = in_sizes[1] / DD;   // 8192

  const size_t split_bytes = (size_t)(n + m) * DD * 2 * sizeof(unsigned short);
  const size_t needed = split_bytes + (size_t)(n + m) * sizeof(float);

  const int nI = n / BM;            // 64
  const int nJ = m / BN;            // 64

  if (ws_size >= needed && nJ % JT == 0) {
    unsigned short* XHg = (unsigned short*)d_ws;
    unsigned short* XLg = XHg + (size_t)n * DD;
    unsigned short* YHg = XLg + (size_t)n * DD;
    unsigned short* YLg = YHg + (size_t)m * DD;
    float* xsq = (float*)(YLg + (size_t)m * DD);
    float* ysq = xsq + n;
    prep_split<<<(n + m) / 16, 256, 0, stream>>>(x, y, XHg, XLg, YHg, YLg, xsq, ysq, n);
    const int jb = nJ / JT;         // 8: matches XCD round-robin
    rbf_persist<<<nI * jb, 256, 0, stream>>>(XHg, XLg, YHg, YLg, g, xsq, ysq, out, m, jb);
  } else {
    float* xsq = (float*)d_ws;
    float* ysq = xsq + n;
    prep_sq<<<(n + m) / 16, 256, 0, stream>>>(x, y, xsq, ysq, n);
    dim3 grid(m / BN, n / BM);
    rbf_mfma_fb<<<grid, 256, 0, stream>>>(x, y, g, xsq, ysq, out, m);
  }
}

// Round 5
// 69.664 us; speedup vs baseline: 1.8197x; 1.8197x over previous
//
#include <hip/hip_runtime.h>
#include <hip/hip_bf16.h>

// RBF kernel matrix: out[i][j] = exp(-gamma * max(x2[i] + y2[j] - 2*x.y, 0))
//
// Round 5: NO-LDS, NO-BARRIER design. prep rewrites X,Y into d_ws as bf16
// hi/lo panels in MFMA-FRAGMENT-LINEAR layout: each 16x32 fragment = 64
// lanes x 16 B contiguous, so every A/B fragment load in the GEMM is one
// perfectly-coalesced global_load_dwordx4 from L2 (4 MB of split inputs is
// L2-resident). Each wave is fully independent -> loads/MFMA/stores
// interleave per-wave, store drains overlap at block turnover (the round-4
// lesson: keep vmcnt(0) drains off the intra-block critical path).
// 3 MFMA passes (hi*hi + lo*hi + hi*lo), drop lo*lo (~1e-21 abs out error).
// Epilogue: out = 2^(min(c*x2 + c*y2 + 2|c|*xy, 0)), c = -g*log2e, regular
// float4 stores (NT stores hurt: they drain to HBM inside vmcnt windows).
// Floor: 268 MB writes @ ~6.9 TB/s (fill-calibrated) ~= 39 us.

#define DD 64
#define BM 128
#define BN 128

typedef __attribute__((ext_vector_type(8))) short short8;
typedef __attribute__((ext_vector_type(4))) float f32x4;

#if __has_builtin(__builtin_amdgcn_exp2f)
#define EXP2(x) __builtin_amdgcn_exp2f(x)
#else
#define EXP2(x) exp2f(x)
#endif

__device__ __forceinline__ unsigned short f2bf_rne(float f) {
  unsigned u = __float_as_uint(f);
  unsigned r = u + 0x7FFFu + ((u >> 16) & 1u);
  return (unsigned short)(r >> 16);
}

// Fragment-linear index (in short8 units): panel p, k-step s, row-block rb,
// lane = hg*16+lr. Lane holds row rb*16+lr, k = s*32+hg*8 .. +8.
__device__ __forceinline__ long fidx(int p, int s, int rb) {
  return ((((long)p * 2 + s) * 8) + rb) * 64;
}

// ---------------- prep: norms + hi/lo split into fragment-linear layout ----
// One thread = one (row, chunk) pair; chunk = 8 consecutive k (16 B lane slot).
__global__ __launch_bounds__(256)
void prep_frag(const float* __restrict__ X, const float* __restrict__ Y,
               short8* __restrict__ XHf, short8* __restrict__ XLf,
               short8* __restrict__ YHf, short8* __restrict__ YLf,
               float* __restrict__ xsq, float* __restrict__ ysq, int n) {
  int t = blockIdx.x * 256 + threadIdx.x;
  int row_g = t >> 3;
  int chunk = t & 7;             // s = chunk>>2, hg = chunk&3
  const float* src;
  short8 *hb, *lb;
  float* nd;
  int r;
  if (row_g < n) { r = row_g;     src = X; hb = XHf; lb = XLf; nd = xsq; }
  else           { r = row_g - n; src = Y; hb = YHf; lb = YLf; nd = ysq; }
  const float* p = src + (long)r * DD + chunk * 8;
  float4 v0 = ((const float4*)p)[0];
  float4 v1 = ((const float4*)p)[1];
  float f[8] = {v0.x, v0.y, v0.z, v0.w, v1.x, v1.y, v1.z, v1.w};

  short8 h8, l8;
  float ss = 0.f;
#pragma unroll
  for (int q = 0; q < 8; ++q) {
    unsigned short h = f2bf_rne(f[q]);
    float hv = __uint_as_float(((unsigned)h) << 16);
    h8[q] = (short)h;
    l8[q] = (short)f2bf_rne(f[q] - hv);
    ss = fmaf(f[q], f[q], ss);
  }
  int pn = r >> 7, rb = (r >> 4) & 7, lr = r & 15;
  int s = chunk >> 2, hg = chunk & 3;
  long o = fidx(pn, s, rb) + hg * 16 + lr;
  hb[o] = h8;
  lb[o] = l8;
  // row norm: 8 threads per row are consecutive lanes
  ss += __shfl_xor(ss, 1);
  ss += __shfl_xor(ss, 2);
  ss += __shfl_xor(ss, 4);
  if (chunk == 0) nd[r] = ss;
}

// ---------------- main: no-LDS MFMA GEMM, frag loads straight from L2 ------
__global__ __launch_bounds__(256, 2)
void rbf_nolds(const short8* __restrict__ XHf, const short8* __restrict__ XLf,
               const short8* __restrict__ YHf, const short8* __restrict__ YLf,
               const float* __restrict__ gptr,
               const float* __restrict__ xsq, const float* __restrict__ ysq,
               float* __restrict__ Out, int mcols) {
  const int tid = threadIdx.x;
  const int lane = tid & 63;
  const int wid = tid >> 6;          // 0..3
  const int wr = wid >> 1, wc = wid & 1;
  const int lr = lane & 15;
  const int hg = lane >> 4;
  const int ip = blockIdx.y;         // X panel
  const int jp = blockIdx.x;         // Y panel
  const long i0 = (long)ip * BM;
  const long j0 = (long)jp * BN;

  // ---- load all fragments (32 coalesced dwordx4 per wave; order = use order)
  short8 ah[2][4], bh[2][4], al[2][4], bl[2][4];
#pragma unroll
  for (int s = 0; s < 2; ++s)
#pragma unroll
    for (int q = 0; q < 4; ++q) {
      ah[s][q] = XHf[fidx(ip, s, wr * 4 + q) + lane];
      bh[s][q] = YHf[fidx(jp, s, wc * 4 + q) + lane];
    }
#pragma unroll
  for (int s = 0; s < 2; ++s)
#pragma unroll
    for (int q = 0; q < 4; ++q) {
      al[s][q] = XLf[fidx(ip, s, wr * 4 + q) + lane];
      bl[s][q] = YLf[fidx(jp, s, wc * 4 + q) + lane];
    }

  f32x4 acc[4][4];
#pragma unroll
  for (int a = 0; a < 4; ++a)
#pragma unroll
    for (int c = 0; c < 4; ++c) acc[a][c] = (f32x4){0.f, 0.f, 0.f, 0.f};

  // ---- 3 passes: (YH,XH), (YH,XL), (YL,XH). Swapped operands: A = Y frag
  // (reg dim -> output cols), B = X frag (lane&15 -> output rows).
#pragma unroll
  for (int s = 0; s < 2; ++s)
#pragma unroll
    for (int m2 = 0; m2 < 4; ++m2)
#pragma unroll
      for (int n2 = 0; n2 < 4; ++n2)
        acc[m2][n2] = __builtin_amdgcn_mfma_f32_16x16x32_bf16(bh[s][n2], ah[s][m2], acc[m2][n2], 0, 0, 0);
#pragma unroll
  for (int s = 0; s < 2; ++s)
#pragma unroll
    for (int m2 = 0; m2 < 4; ++m2)
#pragma unroll
      for (int n2 = 0; n2 < 4; ++n2)
        acc[m2][n2] = __builtin_amdgcn_mfma_f32_16x16x32_bf16(bh[s][n2], al[s][m2], acc[m2][n2], 0, 0, 0);
#pragma unroll
  for (int s = 0; s < 2; ++s)
#pragma unroll
    for (int m2 = 0; m2 < 4; ++m2)
#pragma unroll
      for (int n2 = 0; n2 < 4; ++n2)
        acc[m2][n2] = __builtin_amdgcn_mfma_f32_16x16x32_bf16(bl[s][n2], ah[s][m2], acc[m2][n2], 0, 0, 0);

  // ---- epilogue: out = 2^(min(c*x2 + c*y2 + 2|c|*xy, 0)), c = -g*log2e
  const float g = *gptr;
  const float cf = -g * 1.4426950408889634f;
  const float nc2 = -2.0f * cf;
  float cxr[4];
#pragma unroll
  for (int m2 = 0; m2 < 4; ++m2) cxr[m2] = cf * xsq[i0 + wr * 64 + m2 * 16 + lr];
  float4 cyv[4];
#pragma unroll
  for (int n2 = 0; n2 < 4; ++n2) {
    float4 yq = *(const float4*)&ysq[j0 + wc * 64 + n2 * 16 + hg * 4];
    cyv[n2] = make_float4(cf * yq.x, cf * yq.y, cf * yq.z, cf * yq.w);
  }
#pragma unroll
  for (int m2 = 0; m2 < 4; ++m2) {
    long row = i0 + wr * 64 + m2 * 16 + lr;
    float* op = Out + row * (long)mcols + j0 + wc * 64 + hg * 4;
#pragma unroll
    for (int n2 = 0; n2 < 4; ++n2) {
      float cy[4] = {cyv[n2].x, cyv[n2].y, cyv[n2].z, cyv[n2].w};
      float o[4];
#pragma unroll
      for (int j = 0; j < 4; ++j)
        o[j] = EXP2(fminf(fmaf(nc2, acc[m2][n2][j], cxr[m2] + cy[j]), 0.f));
      *(float4*)(op + n2 * 16) = *(float4*)o;
    }
  }
}

// ---------------- fallback (proven round-2 path) ---------------------------
__global__ __launch_bounds__(256)
void prep_sq(const float* __restrict__ X, const float* __restrict__ Y,
             float* __restrict__ xsq, float* __restrict__ ysq, int n) {
  int t = blockIdx.x * 256 + threadIdx.x;
  int row = t >> 4;
  int c = t & 15;
  const float* src;
  float* dst;
  if (row < n) { src = X + (long)row * DD; dst = xsq + row; }
  else         { src = Y + (long)(row - n) * DD; dst = ysq + (row - n); }
  float4 v = ((const float4*)src)[c];
  float s = v.x * v.x + v.y * v.y + v.z * v.z + v.w * v.w;
  s += __shfl_xor(s, 1);
  s += __shfl_xor(s, 2);
  s += __shfl_xor(s, 4);
  s += __shfl_xor(s, 8);
  if (c == 0) *dst = s;
}

__global__ __launch_bounds__(256, 2)
void rbf_mfma_fb(const float* __restrict__ X, const float* __restrict__ Y,
                 const float* __restrict__ gptr,
                 const float* __restrict__ xsq, const float* __restrict__ ysq,
                 float* __restrict__ Out, int mcols) {
  __shared__ unsigned short XH[BM * DD], XL[BM * DD];
  __shared__ unsigned short YH[BN * DD], YL[BN * DD];
  const int tid = threadIdx.x;
  const long i0 = (long)blockIdx.y * BM;
  const long j0 = (long)blockIdx.x * BN;
#pragma unroll
  for (int it = 0; it < 16; ++it) {
    int e = it * 256 + tid;
    int half = e >> 11;
    int idx = e & 2047;
    int row = idx >> 4;
    int c4 = idx & 15;
    const float* src = half ? (Y + (j0 + row) * DD) : (X + (i0 + row) * DD);
    float4 v = ((const float4*)src)[c4];
    float f[4] = {v.x, v.y, v.z, v.w};
    unsigned short h[4], l[4];
#pragma unroll
    for (int q = 0; q < 4; ++q) {
      h[q] = f2bf_rne(f[q]);
      float hv = __uint_as_float(((unsigned)h[q]) << 16);
      l[q] = f2bf_rne(f[q] - hv);
    }
    int sw = (c4 * 8) ^ ((row & 7) << 4);
    unsigned short* Ht = half ? YH : XH;
    unsigned short* Lt = half ? YL : XL;
    *(ushort4*)((char*)Ht + row * 128 + sw) = make_ushort4(h[0], h[1], h[2], h[3]);
    *(ushort4*)((char*)Lt + row * 128 + sw) = make_ushort4(l[0], l[1], l[2], l[3]);
  }
  __syncthreads();
  const int lane = tid & 63;
  const int wid = tid >> 6;
  const int wr = wid >> 1, wc = wid & 1;
  const int lr = lane & 15;
  const int hg = lane >> 4;
  f32x4 acc[4][4];
#pragma unroll
  for (int a = 0; a < 4; ++a)
#pragma unroll
    for (int c = 0; c < 4; ++c) acc[a][c] = (f32x4){0.f, 0.f, 0.f, 0.f};
  const unsigned short* At[3] = {XH, XL, XH};
  const unsigned short* Bt[3] = {YH, YH, YL};
#pragma unroll
  for (int p = 0; p < 3; ++p) {
#pragma unroll
    for (int s = 0; s < 2; ++s) {
      const int kbyte = s * 64 + hg * 16;
      short8 af[4], bfv[4];
#pragma unroll
      for (int m2 = 0; m2 < 4; ++m2) {
        int row = wr * 64 + m2 * 16 + lr;
        af[m2] = *(const short8*)((const char*)At[p] + row * 128 + (kbyte ^ ((row & 7) << 4)));
      }
#pragma unroll
      for (int n2 = 0; n2 < 4; ++n2) {
        int row = wc * 64 + n2 * 16 + lr;
        bfv[n2] = *(const short8*)((const char*)Bt[p] + row * 128 + (kbyte ^ ((row & 7) << 4)));
      }
#pragma unroll
      for (int m2 = 0; m2 < 4; ++m2)
#pragma unroll
        for (int n2 = 0; n2 < 4; ++n2)
          acc[m2][n2] = __builtin_amdgcn_mfma_f32_16x16x32_bf16(af[m2], bfv[n2], acc[m2][n2], 0, 0, 0);
    }
  }
  const float g = *gptr;
  float yv[4];
#pragma unroll
  for (int n2 = 0; n2 < 4; ++n2) yv[n2] = ysq[j0 + wc * 64 + n2 * 16 + lr];
#pragma unroll
  for (int m2 = 0; m2 < 4; ++m2) {
#pragma unroll
    for (int j = 0; j < 4; ++j) {
      long row = i0 + wr * 64 + m2 * 16 + hg * 4 + j;
      float xr = xsq[row];
      float* op = Out + row * (long)mcols + j0 + wc * 64 + lr;
#pragma unroll
      for (int n2 = 0; n2 < 4; ++n2) {
        float d = fmaxf(xr + yv[n2] - 2.0f * acc[m2][n2][j], 0.f);
        op[n2 * 16] = __expf(-g * d);
      }
    }
  }
}

extern "C" void kernel_launch(void* const* d_in, const int* in_sizes, int n_in,
                              void* d_out, int out_size, void* d_ws, size_t ws_size,
                              hipStream_t stream) {
  const float* x = (const float*)d_in[0];
  const float* y = (const float*)d_in[1];
  const float* g = (const float*)d_in[2];
  float* out = (float*)d_out;

  const int n = in_sizes[0] / DD;   // 8192
  const int m = in_sizes[1] / DD;   // 8192

  const size_t split_bytes = (size_t)(n + m) * DD * 2 * sizeof(unsigned short);
  const size_t needed = split_bytes + (size_t)(n + m) * sizeof(float);

  dim3 grid(m / BN, n / BM);        // 64 x 64 = 4096 blocks

  if (ws_size >= needed && (n % BM) == 0 && (m % BN) == 0) {
    short8* XHf = (short8*)d_ws;                    // n*64 bf16 = n*8 short8
    short8* XLf = XHf + (size_t)n * DD / 8;
    short8* YHf = XLf + (size_t)n * DD / 8;
    short8* YLf = YHf + (size_t)m * DD / 8;
    float* xsq = (float*)(YLf + (size_t)m * DD / 8);
    float* ysq = xsq + n;
    prep_frag<<<(n + m) * 8 / 256, 256, 0, stream>>>(x, y, XHf, XLf, YHf, YLf, xsq, ysq, n);
    rbf_nolds<<<grid, 256, 0, stream>>>(XHf, XLf, YHf, YLf, g, xsq, ysq, out, m);
  } else {
    float* xsq = (float*)d_ws;
    float* ysq = xsq + n;
    prep_sq<<<(n + m) / 16, 256, 0, stream>>>(x, y, xsq, ysq, n);
    rbf_mfma_fb<<<grid, 256, 0, stream>>>(x, y, g, xsq, ysq, out, m);
  }
}

// Round 6
// 61.513 us; speedup vs baseline: 2.0608x; 1.1325x over previous
//
#include <hip/hip_runtime.h>
#include <hip/hip_bf16.h>

// RBF kernel matrix: out[i][j] = exp(-gamma * max(x2[i] + y2[j] - 2*x.y, 0))
//
// Round 6: round-3 structure (DMA staging -> LDS, one 128x128 tile per block,
// 3-pass hi/lo MFMA, fused exp epilogue) at DOUBLE occupancy: 512 threads,
// 8 waves of 64x32 (acc 32 VGPR), __launch_bounds__(512,4) caps VGPR at 128
// -> 4 waves/SIMD (2 blocks/CU, 128 KB LDS). Theory: ~56us main at 4.8 TB/s
// effective write BW is latency-bound at 2 waves/SIMD; 4/SIMD overlaps store
// drains/DMA waits (fill kernel: 32 waves/CU hits 6.9 TB/s).
// 3 MFMA passes (hi*hi + lo*hi + hi*lo), drop lo*lo (~1e-21 abs out error).

#define DD 64
#define BM 128
#define BN 128

typedef __attribute__((ext_vector_type(8))) short short8;
typedef __attribute__((ext_vector_type(4))) float f32x4;

#if __has_builtin(__builtin_amdgcn_exp2f)
#define EXP2(x) __builtin_amdgcn_exp2f(x)
#else
#define EXP2(x) exp2f(x)
#endif

__device__ __forceinline__ unsigned short f2bf_rne(float f) {
  unsigned u = __float_as_uint(f);
  unsigned r = u + 0x7FFFu + ((u >> 16) & 1u);
  return (unsigned short)(r >> 16);
}

// ---------------- prep: fp32 norms + bf16 hi/lo pre-split (pre-swizzled) ----
__global__ __launch_bounds__(256)
void prep_split(const float* __restrict__ X, const float* __restrict__ Y,
                unsigned short* __restrict__ XHg, unsigned short* __restrict__ XLg,
                unsigned short* __restrict__ YHg, unsigned short* __restrict__ YLg,
                float* __restrict__ xsq, float* __restrict__ ysq, int n) {
  int t = blockIdx.x * 256 + threadIdx.x;
  int row = t >> 4;       // 16 lanes per row
  int c4 = t & 15;        // float4 index within row
  const float* src;
  unsigned short *hd, *ld;
  float* nd;
  int r;
  if (row < n) { r = row;     src = X + (long)r * DD; hd = XHg; ld = XLg; nd = xsq + r; }
  else         { r = row - n; src = Y + (long)r * DD; hd = YHg; ld = YLg; nd = ysq + r; }
  float4 v = ((const float4*)src)[c4];
  float f[4] = {v.x, v.y, v.z, v.w};
  unsigned short h[4], l[4];
#pragma unroll
  for (int q = 0; q < 4; ++q) {
    h[q] = f2bf_rne(f[q]);
    float hv = __uint_as_float(((unsigned)h[q]) << 16);
    l[q] = f2bf_rne(f[q] - hv);
  }
  int sw = (c4 * 8) ^ ((r & 7) << 4);   // swizzled byte offset within 128-B row
  *(ushort4*)((char*)hd + (long)r * 128 + sw) = make_ushort4(h[0], h[1], h[2], h[3]);
  *(ushort4*)((char*)ld + (long)r * 128 + sw) = make_ushort4(l[0], l[1], l[2], l[3]);
  float s = v.x * v.x + v.y * v.y + v.z * v.z + v.w * v.w;
  s += __shfl_xor(s, 1);
  s += __shfl_xor(s, 2);
  s += __shfl_xor(s, 4);
  s += __shfl_xor(s, 8);
  if (c4 == 0) *nd = s;
}

// ---------------- main: DMA-staged MFMA GEMM, 8 waves of 64x32 -------------
__global__ __launch_bounds__(512, 4)
void rbf_mfma8(const unsigned short* __restrict__ XHg, const unsigned short* __restrict__ XLg,
               const unsigned short* __restrict__ YHg, const unsigned short* __restrict__ YLg,
               const float* __restrict__ gptr,
               const float* __restrict__ xsq, const float* __restrict__ ysq,
               float* __restrict__ Out, int mcols) {
  // 4 tiles of 128 rows x 128 B (swizzled image), 16 KB each = 64 KB.
  __shared__ __align__(128) char lds[65536];

  const int tid = threadIdx.x;
  const int lane = tid & 63;
  const int wid = tid >> 6;        // 0..7
  const long i0 = (long)blockIdx.y * BM;
  const long j0 = (long)blockIdx.x * BN;

  // ---- stage: 4 contiguous 16-KB slices, global_load_lds width 16
  const char* srcs[4] = {(const char*)XHg + i0 * 128, (const char*)XLg + i0 * 128,
                         (const char*)YHg + j0 * 128, (const char*)YLg + j0 * 128};
#pragma unroll
  for (int t4 = 0; t4 < 4; ++t4) {
#pragma unroll
    for (int it = 0; it < 2; ++it) {
      int off = it * 8192 + wid * 1024;           // wave-uniform
      const char* g = srcs[t4] + off + lane * 16; // per-lane global src
      __builtin_amdgcn_global_load_lds(
          (const __attribute__((address_space(1))) void*)g,
          (__attribute__((address_space(3))) void*)(lds + t4 * 16384 + off),
          16, 0, 0);
    }
  }
  __syncthreads();   // compiler drains vmcnt before the barrier

  // ---- MFMA: 3 passes (hi*hi, lo*hi, hi*lo), 2 k-steps of 32 each
  const int wr = wid >> 2;         // 0..1 -> row half (64 rows)
  const int wc = wid & 3;          // 0..3 -> col quarter (32 cols)
  const int lr = lane & 15;
  const int hg = lane >> 4;        // 0..3

  f32x4 acc[4][2];
#pragma unroll
  for (int a = 0; a < 4; ++a)
#pragma unroll
    for (int b = 0; b < 2; ++b) acc[a][b] = (f32x4){0.f, 0.f, 0.f, 0.f};

  const char* At[3] = {lds, lds + 16384, lds};                 // XH, XL, XH
  const char* Bt[3] = {lds + 32768, lds + 32768, lds + 49152}; // YH, YH, YL
#pragma unroll
  for (int p = 0; p < 3; ++p) {
#pragma unroll
    for (int s = 0; s < 2; ++s) {
      const int kbyte = s * 64 + hg * 16;
      short8 af[4], bfv[2];
#pragma unroll
      for (int m2 = 0; m2 < 4; ++m2) {
        int row = wr * 64 + m2 * 16 + lr;
        af[m2] = *(const short8*)(At[p] + row * 128 + (kbyte ^ ((row & 7) << 4)));
      }
#pragma unroll
      for (int n2 = 0; n2 < 2; ++n2) {
        int row = wc * 32 + n2 * 16 + lr;
        bfv[n2] = *(const short8*)(Bt[p] + row * 128 + (kbyte ^ ((row & 7) << 4)));
      }
      // Swapped operands: reg dim = Y rows (output cols), lane&15 = X rows.
#pragma unroll
      for (int m2 = 0; m2 < 4; ++m2)
#pragma unroll
        for (int n2 = 0; n2 < 2; ++n2)
          acc[m2][n2] = __builtin_amdgcn_mfma_f32_16x16x32_bf16(bfv[n2], af[m2], acc[m2][n2], 0, 0, 0);
    }
  }

  // ---- epilogue: out = 2^( min( c*x2 + c*y2 + 2|c|*xy, 0 ) ), c = -g*log2e
  const float g = *gptr;
  const float cf = -g * 1.4426950408889634f;
  const float nc2 = -2.0f * cf;
  float cxr[4];
#pragma unroll
  for (int m2 = 0; m2 < 4; ++m2) cxr[m2] = cf * xsq[i0 + wr * 64 + m2 * 16 + lr];
  float4 cyv[2];
#pragma unroll
  for (int n2 = 0; n2 < 2; ++n2) {
    float4 yq = *(const float4*)&ysq[j0 + wc * 32 + n2 * 16 + hg * 4];
    cyv[n2] = make_float4(cf * yq.x, cf * yq.y, cf * yq.z, cf * yq.w);
  }
#pragma unroll
  for (int m2 = 0; m2 < 4; ++m2) {
    long row = i0 + wr * 64 + m2 * 16 + lr;
    float* op = Out + row * (long)mcols + j0 + wc * 32 + hg * 4;
#pragma unroll
    for (int n2 = 0; n2 < 2; ++n2) {
      float cy[4] = {cyv[n2].x, cyv[n2].y, cyv[n2].z, cyv[n2].w};
      float o[4];
#pragma unroll
      for (int j = 0; j < 4; ++j)
        o[j] = EXP2(fminf(fmaf(nc2, acc[m2][n2][j], cxr[m2] + cy[j]), 0.f));
      *(float4*)(op + n2 * 16) = *(float4*)o;
    }
  }
}

// ---------------- fallback (proven round-2 path) ---------------------------
__global__ __launch_bounds__(256)
void prep_sq(const float* __restrict__ X, const float* __restrict__ Y,
             float* __restrict__ xsq, float* __restrict__ ysq, int n) {
  int t = blockIdx.x * 256 + threadIdx.x;
  int row = t >> 4;
  int c = t & 15;
  const float* src;
  float* dst;
  if (row < n) { src = X + (long)row * DD; dst = xsq + row; }
  else         { src = Y + (long)(row - n) * DD; dst = ysq + (row - n); }
  float4 v = ((const float4*)src)[c];
  float s = v.x * v.x + v.y * v.y + v.z * v.z + v.w * v.w;
  s += __shfl_xor(s, 1);
  s += __shfl_xor(s, 2);
  s += __shfl_xor(s, 4);
  s += __shfl_xor(s, 8);
  if (c == 0) *dst = s;
}

__global__ __launch_bounds__(256, 2)
void rbf_mfma_fb(const float* __restrict__ X, const float* __restrict__ Y,
                 const float* __restrict__ gptr,
                 const float* __restrict__ xsq, const float* __restrict__ ysq,
                 float* __restrict__ Out, int mcols) {
  __shared__ unsigned short XH[BM * DD], XL[BM * DD];
  __shared__ unsigned short YH[BN * DD], YL[BN * DD];
  const int tid = threadIdx.x;
  const long i0 = (long)blockIdx.y * BM;
  const long j0 = (long)blockIdx.x * BN;
#pragma unroll
  for (int it = 0; it < 16; ++it) {
    int e = it * 256 + tid;
    int half = e >> 11;
    int idx = e & 2047;
    int row = idx >> 4;
    int c4 = idx & 15;
    const float* src = half ? (Y + (j0 + row) * DD) : (X + (i0 + row) * DD);
    float4 v = ((const float4*)src)[c4];
    float f[4] = {v.x, v.y, v.z, v.w};
    unsigned short h[4], l[4];
#pragma unroll
    for (int q = 0; q < 4; ++q) {
      h[q] = f2bf_rne(f[q]);
      float hv = __uint_as_float(((unsigned)h[q]) << 16);
      l[q] = f2bf_rne(f[q] - hv);
    }
    int sw = (c4 * 8) ^ ((row & 7) << 4);
    unsigned short* Ht = half ? YH : XH;
    unsigned short* Lt = half ? YL : XL;
    *(ushort4*)((char*)Ht + row * 128 + sw) = make_ushort4(h[0], h[1], h[2], h[3]);
    *(ushort4*)((char*)Lt + row * 128 + sw) = make_ushort4(l[0], l[1], l[2], l[3]);
  }
  __syncthreads();
  const int lane = tid & 63;
  const int wid = tid >> 6;
  const int wr = wid >> 1, wc = wid & 1;
  const int lr = lane & 15;
  const int hg = lane >> 4;
  f32x4 acc[4][4];
#pragma unroll
  for (int a = 0; a < 4; ++a)
#pragma unroll
    for (int c = 0; c < 4; ++c) acc[a][c] = (f32x4){0.f, 0.f, 0.f, 0.f};
  const unsigned short* At[3] = {XH, XL, XH};
  const unsigned short* Bt[3] = {YH, YH, YL};
#pragma unroll
  for (int p = 0; p < 3; ++p) {
#pragma unroll
    for (int s = 0; s < 2; ++s) {
      const int kbyte = s * 64 + hg * 16;
      short8 af[4], bfv[4];
#pragma unroll
      for (int m2 = 0; m2 < 4; ++m2) {
        int row = wr * 64 + m2 * 16 + lr;
        af[m2] = *(const short8*)((const char*)At[p] + row * 128 + (kbyte ^ ((row & 7) << 4)));
      }
#pragma unroll
      for (int n2 = 0; n2 < 4; ++n2) {
        int row = wc * 64 + n2 * 16 + lr;
        bfv[n2] = *(const short8*)((const char*)Bt[p] + row * 128 + (kbyte ^ ((row & 7) << 4)));
      }
#pragma unroll
      for (int m2 = 0; m2 < 4; ++m2)
#pragma unroll
        for (int n2 = 0; n2 < 4; ++n2)
          acc[m2][n2] = __builtin_amdgcn_mfma_f32_16x16x32_bf16(af[m2], bfv[n2], acc[m2][n2], 0, 0, 0);
    }
  }
  const float g = *gptr;
  float yv[4];
#pragma unroll
  for (int n2 = 0; n2 < 4; ++n2) yv[n2] = ysq[j0 + wc * 64 + n2 * 16 + lr];
#pragma unroll
  for (int m2 = 0; m2 < 4; ++m2) {
#pragma unroll
    for (int j = 0; j < 4; ++j) {
      long row = i0 + wr * 64 + m2 * 16 + hg * 4 + j;
      float xr = xsq[row];
      float* op = Out + row * (long)mcols + j0 + wc * 64 + lr;
#pragma unroll
      for (int n2 = 0; n2 < 4; ++n2) {
        float d = fmaxf(xr + yv[n2] - 2.0f * acc[m2][n2][j], 0.f);
        op[n2 * 16] = __expf(-g * d);
      }
    }
  }
}

extern "C" void kernel_launch(void* const* d_in, const int* in_sizes, int n_in,
                              void* d_out, int out_size, void* d_ws, size_t ws_size,
                              hipStream_t stream) {
  const float* x = (const float*)d_in[0];
  const float* y = (const float*)d_in[1];
  const float* g = (const float*)d_in[2];
  float* out = (float*)d_out;

  const int n = in_sizes[0] / DD;   // 8192
  const int m = in_sizes[1] / DD;   // 8192

  const size_t split_bytes = (size_t)(n + m) * DD * 2 * sizeof(unsigned short);
  const size_t needed = split_bytes + (size_t)(n + m) * sizeof(float);

  dim3 grid(m / BN, n / BM);        // 64 x 64 = 4096 blocks

  if (ws_size >= needed && (n % BM) == 0 && (m % BN) == 0) {
    unsigned short* XHg = (unsigned short*)d_ws;
    unsigned short* XLg = XHg + (size_t)n * DD;
    unsigned short* YHg = XLg + (size_t)n * DD;
    unsigned short* YLg = YHg + (size_t)m * DD;
    float* xsq = (float*)(YLg + (size_t)m * DD);
    float* ysq = xsq + n;
    prep_split<<<(n + m) / 16, 256, 0, stream>>>(x, y, XHg, XLg, YHg, YLg, xsq, ysq, n);
    rbf_mfma8<<<grid, 512, 0, stream>>>(XHg, XLg, YHg, YLg, g, xsq, ysq, out, m);
  } else {
    float* xsq = (float*)d_ws;
    float* ysq = xsq + n;
    prep_sq<<<(n + m) / 16, 256, 0, stream>>>(x, y, xsq, ysq, n);
    rbf_mfma_fb<<<grid, 256, 0, stream>>>(x, y, g, xsq, ysq, out, m);
  }
}